// Round 6
// baseline (501.027 us; speedup 1.0000x reference)
//
#include <hip/hip_runtime.h>

// vol [2,160,192,224,1] f32, flow [2,160,192,224,3] f32
// out = warped [2,160,192,224,1] ++ trf(=flow) [2,160,192,224,3], flat f32.
#define DD 160
#define HH 192
#define WW 224

constexpr int BB       = 2;
constexpr int VOXB     = DD * HH * WW;        // 6,881,280
constexpr int NVOX     = BB * VOXB;           // 13,762,560
constexpr int NGROUP   = NVOX / 4;            // 3,440,640 threads, 4 voxels each
constexpr int NWG      = NGROUP / 256;        // 13,440 workgroups (exact)
constexpr int WG_PER_XCD = NWG / 8;           // 1,680 (exact -> bijective swizzle)

typedef float f32x4 __attribute__((ext_vector_type(4)));

// 8B pair load (4B-aligned); memcpy lets clang emit the widest legal load.
struct F2 { float lo, hi; };
__device__ __forceinline__ F2 load_pair(const float* __restrict__ p) {
    F2 r;
    __builtin_memcpy(&r, p, sizeof(F2));
    return r;
}

struct DimW { int i0, i1; float wlo, whi; };

// neurite interpn fill_value=None (edge clamp):
// cl = clip(loc,0,mx); l0 = clip(floor(loc),0,mx); l1 = clip(l0+1,0,mx)
// wlo = l1 - cl ; whi = 1 - wlo.  Note: loc >= mx  =>  wlo == 0 exactly,
// which makes the min(i0, WW-2) pair-load base safe at the high edge.
__device__ __forceinline__ DimW dimcalc(float loc, float mx) {
    float cl = fminf(fmaxf(loc, 0.0f), mx);
    float l0 = fminf(fmaxf(floorf(loc), 0.0f), mx);
    float l1 = fminf(l0 + 1.0f, mx);
    DimW d;
    d.i0  = (int)l0;
    d.i1  = (int)l1;
    d.wlo = l1 - cl;
    d.whi = 1.0f - d.wlo;
    return d;
}

// R4 post-mortem: launch_bounds(256,4) is only a MINIMUM waves/EU; the
// scheduler still chased 8 waves/SIMD (<=64 VGPR) and allocated 40 VGPRs,
// serializing the gathers (~3 in flight). waves_per_eu(4,4) pins the target:
// VGPR budget 128, 16 waves/CU -> all 16 pair-loads can be in flight.
__global__ __launch_bounds__(256) __attribute__((amdgpu_waves_per_eu(4, 4)))
void st_warp_kernel(
    const float* __restrict__ vol,
    const float* __restrict__ flow,
    float* __restrict__ out_warp,
    float* __restrict__ out_flow)
{
    // XCD-chunked swizzle (bijective: 13440 % 8 == 0): each XCD owns a
    // contiguous z-span so plane re-reads hit its own L2 (R4: FETCH 298->136MB).
    const int wg  = blockIdx.x;
    const int swz = (wg & 7) * WG_PER_XCD + (wg >> 3);
    const int g   = swz * 256 + (int)threadIdx.x;   // exact grid, no tail

    const int i0 = g * 4;                 // first voxel of this 4-group
    const int b  = i0 / VOXB;
    const int r  = i0 % VOXB;
    const int z  = r / (HH * WW);
    const int r2 = r % (HH * WW);
    const int y  = r2 / WW;
    const int x0 = r2 % WW;               // WW % 4 == 0 -> group shares b,z,y

    // flow: 12 consecutive floats, 16B-aligned; streamed once -> non-temporal.
    const f32x4* fl = reinterpret_cast<const f32x4*>(flow) + (size_t)g * 3;
    const f32x4 fA = __builtin_nontemporal_load(fl + 0);
    const f32x4 fB = __builtin_nontemporal_load(fl + 1);
    const f32x4 fC = __builtin_nontemporal_load(fl + 2);
    const float fr[12] = {fA.x, fA.y, fA.z, fA.w,
                          fB.x, fB.y, fB.z, fB.w,
                          fC.x, fC.y, fC.z, fC.w};

    const float* __restrict__ volb = vol + (size_t)b * VOXB;

    // ---- phase 1: all indices + weights (no vol loads yet) ----
    DimW dz[4], dy[4];
    int   xb[4];
    float wxlo[4], wxhi[4];
#pragma unroll
    for (int j = 0; j < 4; ++j) {
        const float lz = (float)z        + fr[j * 3 + 0];
        const float ly = (float)y        + fr[j * 3 + 1];
        const float lx = (float)(x0 + j) + fr[j * 3 + 2];
        dz[j] = dimcalc(lz, (float)(DD - 1));
        dy[j] = dimcalc(ly, (float)(HH - 1));
        DimW dx = dimcalc(lx, (float)(WW - 1));
        xb[j]   = min(dx.i0, WW - 2);     // pair [xb, xb+1]; wlo==0 when clamped
        wxlo[j] = dx.wlo;
        wxhi[j] = dx.whi;
    }

    // ---- phase 2: 16 independent pair-loads into named scalars ----
    const float* p00_0 = volb + (dz[0].i0 * HH + dy[0].i0) * WW + xb[0];
    const float* p01_0 = volb + (dz[0].i0 * HH + dy[0].i1) * WW + xb[0];
    const float* p10_0 = volb + (dz[0].i1 * HH + dy[0].i0) * WW + xb[0];
    const float* p11_0 = volb + (dz[0].i1 * HH + dy[0].i1) * WW + xb[0];
    const float* p00_1 = volb + (dz[1].i0 * HH + dy[1].i0) * WW + xb[1];
    const float* p01_1 = volb + (dz[1].i0 * HH + dy[1].i1) * WW + xb[1];
    const float* p10_1 = volb + (dz[1].i1 * HH + dy[1].i0) * WW + xb[1];
    const float* p11_1 = volb + (dz[1].i1 * HH + dy[1].i1) * WW + xb[1];
    const float* p00_2 = volb + (dz[2].i0 * HH + dy[2].i0) * WW + xb[2];
    const float* p01_2 = volb + (dz[2].i0 * HH + dy[2].i1) * WW + xb[2];
    const float* p10_2 = volb + (dz[2].i1 * HH + dy[2].i0) * WW + xb[2];
    const float* p11_2 = volb + (dz[2].i1 * HH + dy[2].i1) * WW + xb[2];
    const float* p00_3 = volb + (dz[3].i0 * HH + dy[3].i0) * WW + xb[3];
    const float* p01_3 = volb + (dz[3].i0 * HH + dy[3].i1) * WW + xb[3];
    const float* p10_3 = volb + (dz[3].i1 * HH + dy[3].i0) * WW + xb[3];
    const float* p11_3 = volb + (dz[3].i1 * HH + dy[3].i1) * WW + xb[3];

    F2 e00_0 = load_pair(p00_0), e01_0 = load_pair(p01_0),
       e10_0 = load_pair(p10_0), e11_0 = load_pair(p11_0);
    F2 e00_1 = load_pair(p00_1), e01_1 = load_pair(p01_1),
       e10_1 = load_pair(p10_1), e11_1 = load_pair(p11_1);
    F2 e00_2 = load_pair(p00_2), e01_2 = load_pair(p01_2),
       e10_2 = load_pair(p10_2), e11_2 = load_pair(p11_2);
    F2 e00_3 = load_pair(p00_3), e01_3 = load_pair(p01_3),
       e10_3 = load_pair(p10_3), e11_3 = load_pair(p11_3);

    // Cluster the 16 gathers into one contiguous VMEM_READ group so a single
    // s_waitcnt covers them (m137 mechanism). Flow loads are dep-pinned earlier.
    __builtin_amdgcn_sched_group_barrier(0x20 /*VMEM_READ*/, 16, 0);

    // ---- phase 3: trilinear combine ----
    float res[4];
    {
        float vx00, vx01, vx10, vx11, vy0, vy1;
        vx00 = e00_0.lo * wxlo[0] + e00_0.hi * wxhi[0];
        vx01 = e01_0.lo * wxlo[0] + e01_0.hi * wxhi[0];
        vx10 = e10_0.lo * wxlo[0] + e10_0.hi * wxhi[0];
        vx11 = e11_0.lo * wxlo[0] + e11_0.hi * wxhi[0];
        vy0 = vx00 * dy[0].wlo + vx01 * dy[0].whi;
        vy1 = vx10 * dy[0].wlo + vx11 * dy[0].whi;
        res[0] = vy0 * dz[0].wlo + vy1 * dz[0].whi;

        vx00 = e00_1.lo * wxlo[1] + e00_1.hi * wxhi[1];
        vx01 = e01_1.lo * wxlo[1] + e01_1.hi * wxhi[1];
        vx10 = e10_1.lo * wxlo[1] + e10_1.hi * wxhi[1];
        vx11 = e11_1.lo * wxlo[1] + e11_1.hi * wxhi[1];
        vy0 = vx00 * dy[1].wlo + vx01 * dy[1].whi;
        vy1 = vx10 * dy[1].wlo + vx11 * dy[1].whi;
        res[1] = vy0 * dz[1].wlo + vy1 * dz[1].whi;

        vx00 = e00_2.lo * wxlo[2] + e00_2.hi * wxhi[2];
        vx01 = e01_2.lo * wxlo[2] + e01_2.hi * wxhi[2];
        vx10 = e10_2.lo * wxlo[2] + e10_2.hi * wxhi[2];
        vx11 = e11_2.lo * wxlo[2] + e11_2.hi * wxhi[2];
        vy0 = vx00 * dy[2].wlo + vx01 * dy[2].whi;
        vy1 = vx10 * dy[2].wlo + vx11 * dy[2].whi;
        res[2] = vy0 * dz[2].wlo + vy1 * dz[2].whi;

        vx00 = e00_3.lo * wxlo[3] + e00_3.hi * wxhi[3];
        vx01 = e01_3.lo * wxlo[3] + e01_3.hi * wxhi[3];
        vx10 = e10_3.lo * wxlo[3] + e10_3.hi * wxhi[3];
        vx11 = e11_3.lo * wxlo[3] + e11_3.hi * wxhi[3];
        vy0 = vx00 * dy[3].wlo + vx01 * dy[3].whi;
        vy1 = vx10 * dy[3].wlo + vx11 * dy[3].whi;
        res[3] = vy0 * dz[3].wlo + vy1 * dz[3].whi;
    }

    // warped output (16B, coalesced, write-once -> non-temporal)
    f32x4 ov;
    ov.x = res[0]; ov.y = res[1]; ov.z = res[2]; ov.w = res[3];
    __builtin_nontemporal_store(ov, reinterpret_cast<f32x4*>(out_warp) + g);

    // trf output = flow passthrough (already in registers)
    f32x4* of = reinterpret_cast<f32x4*>(out_flow) + (size_t)g * 3;
    __builtin_nontemporal_store(fA, of + 0);
    __builtin_nontemporal_store(fB, of + 1);
    __builtin_nontemporal_store(fC, of + 2);
}

extern "C" void kernel_launch(void* const* d_in, const int* in_sizes, int n_in,
                              void* d_out, int out_size, void* d_ws, size_t ws_size,
                              hipStream_t stream) {
    const float* vol  = (const float*)d_in[0];
    const float* flow = (const float*)d_in[1];
    float* out_warp = (float*)d_out;          // NVOX floats
    float* out_flow = (float*)d_out + NVOX;   // 3*NVOX floats

    st_warp_kernel<<<NWG, 256, 0, stream>>>(vol, flow, out_warp, out_flow);
}